// Round 1
// baseline (1339.831 us; speedup 1.0000x reference)
//
#include <hip/hip_runtime.h>
#include <hip/hip_bf16.h>

#define D 64
#define HID 36
#define IN_DIM 192

// ---------------------------------------------------------------------------
// Kernel 1: zero the sent/recv accumulators in workspace
// ---------------------------------------------------------------------------
__global__ void zero_ws_kernel(float4* __restrict__ p, long n4) {
    long i = (long)blockIdx.x * blockDim.x + threadIdx.x;
    long stride = (long)gridDim.x * blockDim.x;
    float4 z = make_float4(0.f, 0.f, 0.f, 0.f);
    for (; i < n4; i += stride) p[i] = z;
}

// ---------------------------------------------------------------------------
// Kernel 2: fused scatter — one pass over edges, accumulate into BOTH
// sent[] (by senders) and recv[] (by receivers).
// One thread per (edge, feature) element: coalesced 256B/edge reads,
// 2 hardware f32 atomics per thread.
// ---------------------------------------------------------------------------
__global__ __launch_bounds__(256) void scatter_kernel(
    const float* __restrict__ edges,
    const int* __restrict__ senders,
    const int* __restrict__ receivers,
    float* __restrict__ sent,
    float* __restrict__ recv,
    long total)   // n_edges * 64
{
    long i = (long)blockIdx.x * blockDim.x + threadIdx.x;
    if (i >= total) return;
    long e = i >> 6;          // edge index (wave-uniform: 64 lanes = 1 edge)
    int  d = (int)(i & 63);   // feature index
    float v = edges[i];
    int s = senders[e];
    int r = receivers[e];
    unsafeAtomicAdd(&sent[(long)s * D + d], v);
    unsafeAtomicAdd(&recv[(long)r * D + d], v);
}

// ---------------------------------------------------------------------------
// Kernel 3: per-node MLP.  feats = [nodes | sent | recv] (192), h = relu(feats@W1+b1),
// out = h@W2+b2.  One thread per node, acc[36] in registers, W1 staged in LDS.
// ---------------------------------------------------------------------------
__global__ __launch_bounds__(256) void mlp_kernel(
    const float* __restrict__ nodes,
    const float* __restrict__ sent,
    const float* __restrict__ recv,
    const float* __restrict__ W1,   // [192][36]
    const float* __restrict__ b1,   // [36]
    const float* __restrict__ W2,   // [36][2]
    const float* __restrict__ b2,   // [2]
    float* __restrict__ out,        // [n][2]
    int n)
{
    __shared__ float sW1[IN_DIM * HID];   // 27.6 KB
    __shared__ float sb1[HID];
    __shared__ float sW2[HID * 2];
    __shared__ float sb2[2];

    for (int t = threadIdx.x; t < IN_DIM * HID; t += blockDim.x) sW1[t] = W1[t];
    if (threadIdx.x < HID)     sb1[threadIdx.x] = b1[threadIdx.x];
    if (threadIdx.x < HID * 2) sW2[threadIdx.x] = W2[threadIdx.x];
    if (threadIdx.x < 2)       sb2[threadIdx.x] = b2[threadIdx.x];
    __syncthreads();

    int node = blockIdx.x * blockDim.x + threadIdx.x;
    if (node >= n) return;

    float acc[HID];
#pragma unroll
    for (int j = 0; j < HID; ++j) acc[j] = sb1[j];

#pragma unroll
    for (int part = 0; part < 3; ++part) {
        const float* f = (part == 0 ? nodes : (part == 1 ? sent : recv)) + (long)node * D;
        const float* w = sW1 + part * D * HID;
        for (int k = 0; k < D; k += 4) {
            float4 fv = *reinterpret_cast<const float4*>(f + k);
#pragma unroll
            for (int j = 0; j < HID; ++j) {
                acc[j] += fv.x * w[(k + 0) * HID + j];
                acc[j] += fv.y * w[(k + 1) * HID + j];
                acc[j] += fv.z * w[(k + 2) * HID + j];
                acc[j] += fv.w * w[(k + 3) * HID + j];
            }
        }
    }

    float o0 = sb2[0], o1 = sb2[1];
#pragma unroll
    for (int j = 0; j < HID; ++j) {
        float h = fmaxf(acc[j], 0.f);
        o0 += h * sW2[j * 2 + 0];
        o1 += h * sW2[j * 2 + 1];
    }
    reinterpret_cast<float2*>(out)[node] = make_float2(o0, o1);
}

// ---------------------------------------------------------------------------
extern "C" void kernel_launch(void* const* d_in, const int* in_sizes, int n_in,
                              void* d_out, int out_size, void* d_ws, size_t ws_size,
                              hipStream_t stream) {
    const float* nodes     = (const float*)d_in[0];
    const float* edges     = (const float*)d_in[1];
    const int*   senders   = (const int*)d_in[2];
    const int*   receivers = (const int*)d_in[3];
    const float* W1        = (const float*)d_in[4];
    const float* b1        = (const float*)d_in[5];
    const float* W2        = (const float*)d_in[6];
    const float* b2        = (const float*)d_in[7];
    float* out = (float*)d_out;

    const int n_nodes = in_sizes[0] / D;     // 100,000
    const long n_edges = in_sizes[2];        // 3,200,000

    float* sent = (float*)d_ws;                        // [n_nodes][64]
    float* recv = sent + (long)n_nodes * D;            // [n_nodes][64]

    // 1) zero accumulators (51.2 MB)
    {
        long n4 = (long)n_nodes * D * 2 / 4;
        int blocks = 2048;
        zero_ws_kernel<<<blocks, 256, 0, stream>>>((float4*)d_ws, n4);
    }

    // 2) fused scatter
    {
        long total = n_edges * D;                       // 204.8M elements
        long blocks = (total + 255) / 256;
        scatter_kernel<<<(int)blocks, 256, 0, stream>>>(edges, senders, receivers,
                                                        sent, recv, total);
    }

    // 3) MLP
    {
        int blocks = (n_nodes + 255) / 256;
        mlp_kernel<<<blocks, 256, 0, stream>>>(nodes, sent, recv,
                                               W1, b1, W2, b2, out, n_nodes);
    }
}